// Round 4
// baseline (540.077 us; speedup 1.0000x reference)
//
#include <hip/hip_runtime.h>
#include <hip/hip_bf16.h>

#define HID 768
#define WROW 1536   // merge_w row stride (floats)
#define NLAB 64
#define NT   24     // K-tiles of 32: 768/32

typedef __attribute__((ext_vector_type(8))) __bf16 bf16x8;
typedef __attribute__((ext_vector_type(4))) float f32x4;

__device__ __forceinline__ bf16x8 pk8(float4 a, float4 b) {
    return (bf16x8){(__bf16)a.x, (__bf16)a.y, (__bf16)a.z, (__bf16)a.w,
                    (__bf16)b.x, (__bf16)b.y, (__bf16)b.z, (__bf16)b.w};
}

__device__ __forceinline__ void async16(const void* g, void* l) {
    __builtin_amdgcn_global_load_lds(
        (const __attribute__((address_space(1))) void*)g,
        (__attribute__((address_space(3))) void*)l,
        16, 0, 0);
}

// ---------------------------------------------------------------------------
// Prepass A: fp32 -> bf16, flat grid-stride over 8-element units.
// ---------------------------------------------------------------------------
__global__ __launch_bounds__(256) void cvtA_kernel(
    const float* __restrict__ src, unsigned short* __restrict__ dst, long n8)
{
    long i = (long)blockIdx.x * 256 + threadIdx.x;
    const long stride = (long)gridDim.x * 256;
    for (; i < n8; i += stride) {
        float4 a = *(const float4*)(src + i * 8);
        float4 b = *(const float4*)(src + i * 8 + 4);
        *(bf16x8*)(dst + i * 8) = pk8(a, b);
    }
}

// Prepass W-left: Wb[j][k] = bf16(W[j][k]), k<768.
__global__ __launch_bounds__(256) void cvtW_kernel(
    const float* __restrict__ W, unsigned short* __restrict__ Wb)
{
    const int u = blockIdx.x * 256 + threadIdx.x;   // 0..73727
    const int j = u / 96;
    const int c = (u % 96) * 8;
    float4 a = *(const float4*)(W + (size_t)j * WROW + c);
    float4 b = *(const float4*)(W + (size_t)j * WROW + c + 4);
    *(bf16x8*)(Wb + (size_t)j * HID + c) = pk8(a, b);
}

// ---------------------------------------------------------------------------
// Kernel 1: P[l][j] = bias[j] + sum_k lf[l][k] * W[j][HID + k]   (all fp32)
// ---------------------------------------------------------------------------
__global__ __launch_bounds__(256) void compute_P_kernel(
    const float* __restrict__ lf, const float* __restrict__ W,
    const float* __restrict__ bias, float* __restrict__ P)
{
    const int j = blockIdx.x;
    const int t = threadIdx.x;
    __shared__ __align__(16) float wrow[HID];
    if (t < 192)
        *(float4*)(wrow + t * 4) =
            *(const float4*)(W + (size_t)j * WROW + HID + t * 4);
    __syncthreads();

    const int lab = t >> 2;
    const int seg = t & 3;
    const float* lfp = lf + lab * HID + seg * 192;
    const float* wp  = wrow + seg * 192;
    float acc = 0.f;
    #pragma unroll 8
    for (int i = 0; i < 192; i += 4) {
        float4 u = *(const float4*)(lfp + i);
        float4 v = *(const float4*)(wp + i);
        acc += u.x * v.x + u.y * v.y + u.z * v.z + u.w * v.w;
    }
    acc += __shfl_xor(acc, 1);
    acc += __shfl_xor(acc, 2);
    if (seg == 0) P[lab * HID + j] = acc + bias[j];
}

// ---------------------------------------------------------------------------
// Kernel 2: 256x256 tile, BK=32, 512 thr = 8 waves (2x4), wave tile 128x64
// (reuse 42.7 FLOP/LDS-byte -> MFMA-bound).  3-deep K-tile LDS pipeline,
// staged 2 ahead with global_load_lds(16B); per K-tile ONE raw s_barrier
// preceded by s_waitcnt vmcnt(4) (drains exactly tile t+1's 4 loads, keeps
// t+2's in flight -- counted, never 0 until tail).  Chunk XOR swizzle
// (chunk ^= (row>>1)&3) applied at the GLOBAL source (LDS dest linear, as
// gload_lds requires) and on the ds_read address -> 2-way (free) frag reads.
// Race audit: slot (kt+2)%3 was last READ at kt-1; all readers passed the
// kt-1 barrier before any wave issues the overwrite at kt.
// ---------------------------------------------------------------------------
__global__ __launch_bounds__(512, 2) void merge_gemm_v2_kernel(
    const unsigned short* __restrict__ Ab,   // [n, 768] bf16 bits
    const float* __restrict__ A,             // [n, 768] fp32 (passthrough)
    const int* __restrict__ labels,          // [n]
    const unsigned short* __restrict__ Wb,   // [768, 768] bf16 bits
    const float* __restrict__ P,             // [64, 768]
    float* __restrict__ out,                 // [n, 768]
    const int nwg)                           // 768
{
    __shared__ __align__(16) unsigned short As[3][256 * 32];  // 16 KB/slot
    __shared__ __align__(16) unsigned short Bs[3][256 * 32];
    __shared__ int Ls[256];

    // bijective XCD-chunk swizzle; consecutive bids (3 j-tiles per m-panel)
    // stay on one XCD -> A-panel L2 reuse.
    int bid = blockIdx.x;
    {
        const int q = nwg >> 3;               // 96
        bid = (bid & 7) * q + (bid >> 3);
    }
    const int m0 = (bid / 3) * 256;
    const int j0 = (bid % 3) * 256;

    const int t = threadIdx.x;
    if (t < 256) Ls[t] = labels[m0 + t];

    const int wid = t >> 6;
    const int l   = t & 63;
    const int lm  = l & 15;
    const int lk  = l >> 4;                   // 0..3
    const int wm  = wid >> 2;                 // 0..1 -> rows wm*128..+128
    const int wn  = wid & 3;                  // 0..3 -> cols wn*64..+64

    // Staging map (per 8KB issue = 128 rows x 4 chunks): thread t -> row
    // t>>2, dest chunk t&3, SOURCE chunk (t&3)^((t>>3)&3)  [pre-swizzle].
    const int srow = t >> 2;
    const int scol = ((t & 3) ^ ((t >> 3) & 3)) * 8;
    const unsigned short* gA = Ab + (size_t)(m0 + srow) * HID + scol;
    const unsigned short* gB = Wb + (size_t)(j0 + srow) * HID + scol;

    // Fragment read swizzle: chunk = lk ^ ((r>>1)&3); (r>>1)&3 == (lm>>1)&3
    // for every frag row r = {wm*128|wn*64} + {mi|ni}*16 + lm  (multiples of
    // 16 and 64 vanish mod 4 after >>1).
    const int kchunk = (lk ^ ((lm >> 1) & 3)) * 8;

    f32x4 acc[8][4] = {};

#define STAGE(slot, KT) do {                                                   \
    const size_t kc = (size_t)(KT) * 32;                                       \
    async16(gA + kc,                      &As[slot][t * 8]);                   \
    async16(gA + (size_t)128 * HID + kc,  &As[slot][4096 + t * 8]);            \
    async16(gB + kc,                      &Bs[slot][t * 8]);                   \
    async16(gB + (size_t)128 * HID + kc,  &Bs[slot][4096 + t * 8]);            \
} while (0)

    STAGE(0, 0);
    STAGE(1, 1);
    __syncthreads();                       // drains vmcnt(0): tiles 0,1 landed

    for (int kt = 0; kt < NT; ++kt) {
        const int b = kt % 3;
        if (kt + 2 < NT) STAGE((kt + 2) % 3, kt + 2);

        bf16x8 af[8], bf[4];
        #pragma unroll
        for (int mi = 0; mi < 8; ++mi)
            af[mi] = *(const bf16x8*)&As[b][(wm * 128 + mi * 16 + lm) * 32 + kchunk];
        #pragma unroll
        for (int ni = 0; ni < 4; ++ni)
            bf[ni] = *(const bf16x8*)&Bs[b][(wn * 64 + ni * 16 + lm) * 32 + kchunk];

        __builtin_amdgcn_s_setprio(1);
        #pragma unroll
        for (int mi = 0; mi < 8; ++mi)
            #pragma unroll
            for (int ni = 0; ni < 4; ++ni)
                acc[mi][ni] = __builtin_amdgcn_mfma_f32_16x16x32_bf16(
                    af[mi], bf[ni], acc[mi][ni], 0, 0, 0);
        __builtin_amdgcn_s_setprio(0);

        // Gate: tile kt+1's 4 loads landed; tile kt+2's may stay in flight.
        if (kt + 2 < NT)
            asm volatile("s_waitcnt vmcnt(4)\n\ts_barrier" ::: "memory");
        else
            asm volatile("s_waitcnt vmcnt(0)\n\ts_barrier" ::: "memory");
    }
#undef STAGE

    // Epilogue. C/D 16x16 layout: col = lane&15, row = (lane>>4)*4 + reg.
    #pragma unroll
    for (int mi = 0; mi < 8; ++mi) {
        const int rowb = wm * 128 + mi * 16 + lk * 4;
        #pragma unroll
        for (int r = 0; r < 4; ++r) {
            const int row   = rowb + r;
            const int lab   = Ls[row];
            const size_t rowoff = (size_t)(m0 + row) * HID;
            #pragma unroll
            for (int ni = 0; ni < 4; ++ni) {
                const int j = j0 + wn * 64 + ni * 16 + lm;
                float v;
                if (lab != 0)
                    v = acc[mi][ni][r] + P[(size_t)(lab - 1) * HID + j];
                else
                    v = A[rowoff + j];
                out[rowoff + j] = v;
            }
        }
    }
}

// ---------------------------------------------------------------------------
// Fallback (ws too small -- not expected; ws >= 102 MB proven in R3).
// ---------------------------------------------------------------------------
__global__ __launch_bounds__(256) void merge_gemm_kernel(
    const float* __restrict__ A, const int* __restrict__ labels,
    const float* __restrict__ W, const float* __restrict__ P,
    float* __restrict__ out, const int nwg)
{
    __shared__ __align__(16) unsigned short As[2][128 * 32];
    __shared__ __align__(16) unsigned short Bs[2][128 * 32];
    __shared__ int Ls[128];

    int bid = blockIdx.x;
    if ((nwg & 7) == 0) {
        const int q = nwg >> 3;
        bid = (bid & 7) * q + (bid >> 3);
    }
    const int m0 = (bid / (HID / 128)) * 128;
    const int j0 = (bid % (HID / 128)) * 128;

    const int t = threadIdx.x;
    if (t < 128) Ls[t] = labels[m0 + t];

    const int w  = t >> 6;
    const int l  = t & 63;
    const int lm = l & 15;
    const int lk = l >> 4;
    const int qm = (w >> 1) * 64;
    const int qn = (w & 1) * 64;

    const int sr = t >> 2;
    const int sc = t & 3;
    const float* gA  = A + (size_t)(m0 + sr) * HID  + sc * 8;
    const float* gA2 = gA + (size_t)64 * HID;
    const float* gB  = W + (size_t)(j0 + sr) * WROW + sc * 8;
    const float* gB2 = gB + (size_t)64 * WROW;
    const int eoff = sr * 32 + ((sc ^ (sr & 3)) * 8);

    float4 ra0, ra1, ra2, ra3, rb0, rb1, rb2, rb3;
    f32x4 acc[4][4] = {};

#define ISSUE(K) do { \
    ra0 = *(const float4*)(gA  + (K));      ra1 = *(const float4*)(gA  + (K) + 4); \
    ra2 = *(const float4*)(gA2 + (K));      ra3 = *(const float4*)(gA2 + (K) + 4); \
    rb0 = *(const float4*)(gB  + (K));      rb1 = *(const float4*)(gB  + (K) + 4); \
    rb2 = *(const float4*)(gB2 + (K));      rb3 = *(const float4*)(gB2 + (K) + 4); \
} while (0)

    ISSUE(0);
    int p = 0;
    for (int k0 = 0; k0 < HID; k0 += 32) {
        *(bf16x8*)&As[p][eoff]        = pk8(ra0, ra1);
        *(bf16x8*)&As[p][eoff + 2048] = pk8(ra2, ra3);
        *(bf16x8*)&Bs[p][eoff]        = pk8(rb0, rb1);
        *(bf16x8*)&Bs[p][eoff + 2048] = pk8(rb2, rb3);
        if (k0 + 32 < HID) ISSUE(k0 + 32);
        __syncthreads();

        bf16x8 af[4], bfr[4];
        #pragma unroll
        for (int mi = 0; mi < 4; ++mi) {
            const int r = qm + mi * 16 + lm;
            af[mi] = *(const bf16x8*)&As[p][r * 32 + ((lk ^ (r & 3)) * 8)];
        }
        #pragma unroll
        for (int ni = 0; ni < 4; ++ni) {
            const int r = qn + ni * 16 + lm;
            bfr[ni] = *(const bf16x8*)&Bs[p][r * 32 + ((lk ^ (r & 3)) * 8)];
        }
        #pragma unroll
        for (int mi = 0; mi < 4; ++mi)
            #pragma unroll
            for (int ni = 0; ni < 4; ++ni)
                acc[mi][ni] = __builtin_amdgcn_mfma_f32_16x16x32_bf16(
                    af[mi], bfr[ni], acc[mi][ni], 0, 0, 0);
        p ^= 1;
    }
#undef ISSUE

    #pragma unroll
    for (int mi = 0; mi < 4; ++mi) {
        const int rowb = qm + mi * 16 + lk * 4;
        #pragma unroll
        for (int r = 0; r < 4; ++r) {
            const int lab   = Ls[rowb + r];
            const size_t rowoff = (size_t)(m0 + rowb + r) * HID;
            #pragma unroll
            for (int ni = 0; ni < 4; ++ni) {
                const int j = j0 + qn + ni * 16 + lm;
                float v;
                if (lab != 0)
                    v = acc[mi][ni][r] + P[(size_t)(lab - 1) * HID + j];
                else
                    v = A[rowoff + j];
                out[rowoff + j] = v;
            }
        }
    }
}

extern "C" void kernel_launch(void* const* d_in, const int* in_sizes, int n_in,
                              void* d_out, int out_size, void* d_ws, size_t ws_size,
                              hipStream_t stream) {
    const float* com    = (const float*)d_in[0];
    const int*   labels = (const int*)d_in[1];
    const float* lf     = (const float*)d_in[2];
    const float* W      = (const float*)d_in[3];
    const float* bias   = (const float*)d_in[4];
    float* out = (float*)d_out;

    const int n_rows = in_sizes[0] / HID;         // 65536

    // ws layout: P fp32 [64*768] | Wb bf16 [768*768] | Ab bf16 [n_rows*768]
    float* P = (float*)d_ws;
    const size_t off_Wb = (size_t)NLAB * HID * 4;
    const size_t off_Ab = off_Wb + (size_t)HID * HID * 2;
    const size_t need   = off_Ab + (size_t)n_rows * HID * 2;

    if (ws_size >= need) {
        unsigned short* Wb = (unsigned short*)((char*)d_ws + off_Wb);
        unsigned short* Ab = (unsigned short*)((char*)d_ws + off_Ab);
        const long n8 = (long)n_rows * HID / 8;
        cvtA_kernel<<<dim3(2048), dim3(256), 0, stream>>>(com, Ab, n8);
        cvtW_kernel<<<dim3(HID * 96 / 256), dim3(256), 0, stream>>>(W, Wb);
        compute_P_kernel<<<dim3(HID), dim3(256), 0, stream>>>(lf, W, bias, P);
        const int nwg = (n_rows / 256) * (HID / 256);   // 768
        merge_gemm_v2_kernel<<<dim3(nwg), dim3(512), 0, stream>>>(
            Ab, com, labels, Wb, P, out, nwg);
    } else {
        compute_P_kernel<<<dim3(HID), dim3(256), 0, stream>>>(lf, W, bias, P);
        const int nwg = (n_rows / 128) * (HID / 128);
        merge_gemm_kernel<<<dim3(nwg), dim3(256), 0, stream>>>(
            com, labels, W, P, out, nwg);
    }
}

// Round 5
// 510.872 us; speedup vs baseline: 1.0572x; 1.0572x over previous
//
#include <hip/hip_runtime.h>
#include <hip/hip_bf16.h>

#define HID 768
#define WROW 1536   // merge_w row stride (floats)
#define NLAB 64
#define NT   24     // K-tiles of 32: 768/32

typedef __attribute__((ext_vector_type(8))) __bf16 bf16x8;
typedef __attribute__((ext_vector_type(4))) float f32x4;

__device__ __forceinline__ bf16x8 pk8(float4 a, float4 b) {
    return (bf16x8){(__bf16)a.x, (__bf16)a.y, (__bf16)a.z, (__bf16)a.w,
                    (__bf16)b.x, (__bf16)b.y, (__bf16)b.z, (__bf16)b.w};
}

__device__ __forceinline__ void async16(const void* g, void* l) {
    __builtin_amdgcn_global_load_lds(
        (const __attribute__((address_space(1))) void*)g,
        (__attribute__((address_space(3))) void*)l,
        16, 0, 0);
}

// ---------------------------------------------------------------------------
// Prepass A: fp32 -> bf16, flat grid-stride over 8-element units.
// ---------------------------------------------------------------------------
__global__ __launch_bounds__(256) void cvtA_kernel(
    const float* __restrict__ src, unsigned short* __restrict__ dst, long n8)
{
    long i = (long)blockIdx.x * 256 + threadIdx.x;
    const long stride = (long)gridDim.x * 256;
    for (; i < n8; i += stride) {
        float4 a = *(const float4*)(src + i * 8);
        float4 b = *(const float4*)(src + i * 8 + 4);
        *(bf16x8*)(dst + i * 8) = pk8(a, b);
    }
}

// Prepass W-left: Wb[j][k] = bf16(W[j][k]), k<768.
__global__ __launch_bounds__(256) void cvtW_kernel(
    const float* __restrict__ W, unsigned short* __restrict__ Wb)
{
    const int u = blockIdx.x * 256 + threadIdx.x;   // 0..73727
    const int j = u / 96;
    const int c = (u % 96) * 8;
    float4 a = *(const float4*)(W + (size_t)j * WROW + c);
    float4 b = *(const float4*)(W + (size_t)j * WROW + c + 4);
    *(bf16x8*)(Wb + (size_t)j * HID + c) = pk8(a, b);
}

// ---------------------------------------------------------------------------
// Kernel 1: P[l][j] = bias[j] + sum_k lf[l][k] * W[j][HID + k]   (all fp32)
// ---------------------------------------------------------------------------
__global__ __launch_bounds__(256) void compute_P_kernel(
    const float* __restrict__ lf, const float* __restrict__ W,
    const float* __restrict__ bias, float* __restrict__ P)
{
    const int j = blockIdx.x;
    const int t = threadIdx.x;
    __shared__ __align__(16) float wrow[HID];
    if (t < 192)
        *(float4*)(wrow + t * 4) =
            *(const float4*)(W + (size_t)j * WROW + HID + t * 4);
    __syncthreads();

    const int lab = t >> 2;
    const int seg = t & 3;
    const float* lfp = lf + lab * HID + seg * 192;
    const float* wp  = wrow + seg * 192;
    float acc = 0.f;
    #pragma unroll 8
    for (int i = 0; i < 192; i += 4) {
        float4 u = *(const float4*)(lfp + i);
        float4 v = *(const float4*)(wp + i);
        acc += u.x * v.x + u.y * v.y + u.z * v.z + u.w * v.w;
    }
    acc += __shfl_xor(acc, 1);
    acc += __shfl_xor(acc, 2);
    if (seg == 0) P[lab * HID + j] = acc + bias[j];
}

// ---------------------------------------------------------------------------
// Kernel 2 v3: 256x256 tile, BK=32, 512 thr = 8 waves (2x4), wave tile
// 128x64.  3-deep K-tile pipeline with STATICALLY-NAMED LDS slots and a
// fully unrolled K-loop: write-slot and read-slot are distinct objects at
// compile time, so the compiler cannot insert a conservative vmcnt(0)
// before the fragment ds_reads (the suspected R3/R4 stall).  The ONLY
// vmem gate is the hand-written counted s_waitcnt vmcnt(4) per K-tile
// (drains exactly tile kt+1's 4 loads, keeps kt+2's in flight).
// Race audit: slot s's readers at tile kt all pass the end-of-kt barrier
// before any wave issues the overwrite of s at tile kt+1.
// ---------------------------------------------------------------------------
__global__ __launch_bounds__(512, 2) void merge_gemm_v3_kernel(
    const unsigned short* __restrict__ Ab,   // [n, 768] bf16 bits
    const float* __restrict__ A,             // [n, 768] fp32 (passthrough)
    const int* __restrict__ labels,          // [n]
    const unsigned short* __restrict__ Wb,   // [768, 768] bf16 bits
    const float* __restrict__ P,             // [64, 768]
    float* __restrict__ out,                 // [n, 768]
    const int nwg)                           // 768
{
    __shared__ __align__(16) unsigned short As0[256 * 32];  // 16 KB each
    __shared__ __align__(16) unsigned short As1[256 * 32];
    __shared__ __align__(16) unsigned short As2[256 * 32];
    __shared__ __align__(16) unsigned short Bs0[256 * 32];
    __shared__ __align__(16) unsigned short Bs1[256 * 32];
    __shared__ __align__(16) unsigned short Bs2[256 * 32];
    __shared__ int Ls[256];

    int bid = blockIdx.x;
    {
        const int q = nwg >> 3;               // 96
        bid = (bid & 7) * q + (bid >> 3);
    }
    const int m0 = (bid / 3) * 256;
    const int j0 = (bid % 3) * 256;

    const int t = threadIdx.x;
    if (t < 256) Ls[t] = labels[m0 + t];

    const int wid = t >> 6;
    const int l   = t & 63;
    const int lm  = l & 15;
    const int lk  = l >> 4;                   // 0..3
    const int wm  = wid >> 2;                 // 0..1 -> rows wm*128..+128
    const int wn  = wid & 3;                  // 0..3 -> cols wn*64..+64

    // Staging: thread t -> row t>>2 (and +128), dest chunk t&3 (linear),
    // SOURCE chunk (t&3)^((row>>1)&3)  [pre-swizzle; (t>>3)&3 == (row>>1)&3].
    const int srow = t >> 2;
    const int scol = ((t & 3) ^ ((t >> 3) & 3)) * 8;
    const unsigned short* gA = Ab + (size_t)(m0 + srow) * HID + scol;
    const unsigned short* gB = Wb + (size_t)(j0 + srow) * HID + scol;

    // Fragment read swizzle: chunk = lk ^ ((r>>1)&3) = lk ^ ((lm>>1)&3)
    // for all frag rows r = base16 + lm.
    const int kchunk = (lk ^ ((lm >> 1) & 3)) * 8;

    f32x4 acc[8][4] = {};

#define STAGE_(AS, BS, KT) do {                                               \
    const size_t kc = (size_t)(KT) * 32;                                      \
    async16(gA + kc,                      &AS[t * 8]);                        \
    async16(gA + (size_t)128 * HID + kc,  &AS[4096 + t * 8]);                 \
    async16(gB + kc,                      &BS[t * 8]);                        \
    async16(gB + (size_t)128 * HID + kc,  &BS[4096 + t * 8]);                 \
} while (0)

#define COMPUTE_(AS, BS) do {                                                 \
    bf16x8 af[8], bfv[4];                                                     \
    _Pragma("unroll")                                                         \
    for (int mi = 0; mi < 8; ++mi)                                            \
        af[mi] = *(const bf16x8*)&AS[(wm * 128 + mi * 16 + lm) * 32 + kchunk];\
    _Pragma("unroll")                                                         \
    for (int ni = 0; ni < 4; ++ni)                                            \
        bfv[ni] = *(const bf16x8*)&BS[(wn * 64 + ni * 16 + lm) * 32 + kchunk];\
    __builtin_amdgcn_s_setprio(1);                                            \
    _Pragma("unroll")                                                         \
    for (int mi = 0; mi < 8; ++mi)                                            \
        _Pragma("unroll")                                                     \
        for (int ni = 0; ni < 4; ++ni)                                        \
            acc[mi][ni] = __builtin_amdgcn_mfma_f32_16x16x32_bf16(            \
                af[mi], bfv[ni], acc[mi][ni], 0, 0, 0);                       \
    __builtin_amdgcn_s_setprio(0);                                            \
} while (0)

#define GATE4 asm volatile("s_waitcnt vmcnt(4)\n\ts_barrier" ::: "memory")
#define GATE0 asm volatile("s_waitcnt vmcnt(0)\n\ts_barrier" ::: "memory")

#define ITER(CA, CB, NA, NB, KT2) do { STAGE_(NA, NB, KT2); COMPUTE_(CA, CB); GATE4; } while (0)
#define ROUND3(KT)                          \
    ITER(As0, Bs0, As2, Bs2, (KT) + 2);     \
    ITER(As1, Bs1, As0, Bs0, (KT) + 3);     \
    ITER(As2, Bs2, As1, Bs1, (KT) + 4);

    STAGE_(As0, Bs0, 0);
    STAGE_(As1, Bs1, 1);
    // Drain tile 0 (4 loads stay in flight) + Ls ds_write visibility.
    asm volatile("s_waitcnt vmcnt(4) lgkmcnt(0)\n\ts_barrier" ::: "memory");

    ROUND3(0)   // kt 0..2   (stages tiles 2..4)
    ROUND3(3)   // kt 3..5
    ROUND3(6)   // kt 6..8
    ROUND3(9)   // kt 9..11
    ROUND3(12)  // kt 12..14
    ROUND3(15)  // kt 15..17
    ROUND3(18)  // kt 18..20 (stages tiles 20..22)
    ITER(As0, Bs0, As2, Bs2, 23);   // kt 21, stages last tile 23
    COMPUTE_(As1, Bs1);             // kt 22
    GATE0;                          // drain tile 23's 4 loads
    COMPUTE_(As2, Bs2);             // kt 23

#undef ROUND3
#undef ITER
#undef GATE0
#undef GATE4
#undef COMPUTE_
#undef STAGE_

    // Epilogue. C/D 16x16 layout: col = lane&15, row = (lane>>4)*4 + reg.
    #pragma unroll
    for (int mi = 0; mi < 8; ++mi) {
        const int rowb = wm * 128 + mi * 16 + lk * 4;
        #pragma unroll
        for (int r = 0; r < 4; ++r) {
            const int row   = rowb + r;
            const int lab   = Ls[row];
            const size_t rowoff = (size_t)(m0 + row) * HID;
            #pragma unroll
            for (int ni = 0; ni < 4; ++ni) {
                const int j = j0 + wn * 64 + ni * 16 + lm;
                float v;
                if (lab != 0)
                    v = acc[mi][ni][r] + P[(size_t)(lab - 1) * HID + j];
                else
                    v = A[rowoff + j];
                out[rowoff + j] = v;
            }
        }
    }
}

// ---------------------------------------------------------------------------
// Fallback (ws too small -- not expected; ws >= 102 MB proven in R3/R4).
// ---------------------------------------------------------------------------
__global__ __launch_bounds__(256) void merge_gemm_kernel(
    const float* __restrict__ A, const int* __restrict__ labels,
    const float* __restrict__ W, const float* __restrict__ P,
    float* __restrict__ out, const int nwg)
{
    __shared__ __align__(16) unsigned short As[2][128 * 32];
    __shared__ __align__(16) unsigned short Bs[2][128 * 32];
    __shared__ int Ls[128];

    int bid = blockIdx.x;
    if ((nwg & 7) == 0) {
        const int q = nwg >> 3;
        bid = (bid & 7) * q + (bid >> 3);
    }
    const int m0 = (bid / (HID / 128)) * 128;
    const int j0 = (bid % (HID / 128)) * 128;

    const int t = threadIdx.x;
    if (t < 128) Ls[t] = labels[m0 + t];

    const int w  = t >> 6;
    const int l  = t & 63;
    const int lm = l & 15;
    const int lk = l >> 4;
    const int qm = (w >> 1) * 64;
    const int qn = (w & 1) * 64;

    const int sr = t >> 2;
    const int sc = t & 3;
    const float* gA  = A + (size_t)(m0 + sr) * HID  + sc * 8;
    const float* gA2 = gA + (size_t)64 * HID;
    const float* gB  = W + (size_t)(j0 + sr) * WROW + sc * 8;
    const float* gB2 = gB + (size_t)64 * WROW;
    const int eoff = sr * 32 + ((sc ^ (sr & 3)) * 8);

    float4 ra0, ra1, ra2, ra3, rb0, rb1, rb2, rb3;
    f32x4 acc[4][4] = {};

#define ISSUE(K) do { \
    ra0 = *(const float4*)(gA  + (K));      ra1 = *(const float4*)(gA  + (K) + 4); \
    ra2 = *(const float4*)(gA2 + (K));      ra3 = *(const float4*)(gA2 + (K) + 4); \
    rb0 = *(const float4*)(gB  + (K));      rb1 = *(const float4*)(gB  + (K) + 4); \
    rb2 = *(const float4*)(gB2 + (K));      rb3 = *(const float4*)(gB2 + (K) + 4); \
} while (0)

    ISSUE(0);
    int p = 0;
    for (int k0 = 0; k0 < HID; k0 += 32) {
        *(bf16x8*)&As[p][eoff]        = pk8(ra0, ra1);
        *(bf16x8*)&As[p][eoff + 2048] = pk8(ra2, ra3);
        *(bf16x8*)&Bs[p][eoff]        = pk8(rb0, rb1);
        *(bf16x8*)&Bs[p][eoff + 2048] = pk8(rb2, rb3);
        if (k0 + 32 < HID) ISSUE(k0 + 32);
        __syncthreads();

        bf16x8 af[4], bfr[4];
        #pragma unroll
        for (int mi = 0; mi < 4; ++mi) {
            const int r = qm + mi * 16 + lm;
            af[mi] = *(const bf16x8*)&As[p][r * 32 + ((lk ^ (r & 3)) * 8)];
        }
        #pragma unroll
        for (int ni = 0; ni < 4; ++ni) {
            const int r = qn + ni * 16 + lm;
            bfr[ni] = *(const bf16x8*)&Bs[p][r * 32 + ((lk ^ (r & 3)) * 8)];
        }
        #pragma unroll
        for (int mi = 0; mi < 4; ++mi)
            #pragma unroll
            for (int ni = 0; ni < 4; ++ni)
                acc[mi][ni] = __builtin_amdgcn_mfma_f32_16x16x32_bf16(
                    af[mi], bfr[ni], acc[mi][ni], 0, 0, 0);
        p ^= 1;
    }
#undef ISSUE

    #pragma unroll
    for (int mi = 0; mi < 4; ++mi) {
        const int rowb = qm + mi * 16 + lk * 4;
        #pragma unroll
        for (int r = 0; r < 4; ++r) {
            const int lab   = Ls[rowb + r];
            const size_t rowoff = (size_t)(m0 + rowb + r) * HID;
            #pragma unroll
            for (int ni = 0; ni < 4; ++ni) {
                const int j = j0 + qn + ni * 16 + lm;
                float v;
                if (lab != 0)
                    v = acc[mi][ni][r] + P[(size_t)(lab - 1) * HID + j];
                else
                    v = A[rowoff + j];
                out[rowoff + j] = v;
            }
        }
    }
}

extern "C" void kernel_launch(void* const* d_in, const int* in_sizes, int n_in,
                              void* d_out, int out_size, void* d_ws, size_t ws_size,
                              hipStream_t stream) {
    const float* com    = (const float*)d_in[0];
    const int*   labels = (const int*)d_in[1];
    const float* lf     = (const float*)d_in[2];
    const float* W      = (const float*)d_in[3];
    const float* bias   = (const float*)d_in[4];
    float* out = (float*)d_out;

    const int n_rows = in_sizes[0] / HID;         // 65536

    // ws layout: P fp32 [64*768] | Wb bf16 [768*768] | Ab bf16 [n_rows*768]
    float* P = (float*)d_ws;
    const size_t off_Wb = (size_t)NLAB * HID * 4;
    const size_t off_Ab = off_Wb + (size_t)HID * HID * 2;
    const size_t need   = off_Ab + (size_t)n_rows * HID * 2;

    if (ws_size >= need) {
        unsigned short* Wb = (unsigned short*)((char*)d_ws + off_Wb);
        unsigned short* Ab = (unsigned short*)((char*)d_ws + off_Ab);
        const long n8 = (long)n_rows * HID / 8;
        cvtA_kernel<<<dim3(2048), dim3(256), 0, stream>>>(com, Ab, n8);
        cvtW_kernel<<<dim3(HID * 96 / 256), dim3(256), 0, stream>>>(W, Wb);
        compute_P_kernel<<<dim3(HID), dim3(256), 0, stream>>>(lf, W, bias, P);
        const int nwg = (n_rows / 256) * (HID / 256);   // 768
        merge_gemm_v3_kernel<<<dim3(nwg), dim3(512), 0, stream>>>(
            Ab, com, labels, Wb, P, out, nwg);
    } else {
        compute_P_kernel<<<dim3(HID), dim3(256), 0, stream>>>(lf, W, bias, P);
        const int nwg = (n_rows / 128) * (HID / 128);
        merge_gemm_kernel<<<dim3(nwg), dim3(256), 0, stream>>>(
            com, labels, W, P, out, nwg);
    }
}